// Round 1
// baseline (508.245 us; speedup 1.0000x reference)
//
#include <hip/hip_runtime.h>
#include <math.h>

// Problem shape (fixed by reference setup_inputs):
//   predictions, ground_truths: [BS=16, SEQ=4096, SRC=4, DIM=257] float32
//   out = sum over (b,src) of sqrt( sum over (seq,dim) diff^2 )
#define BS   16
#define SEQ  4096
#define SRC  4
#define DIM  257
#define NBUCKET (BS * SRC)          // 64
#define CHUNKS 32                   // blocks per bucket along seq
#define ROWS_PER_BLOCK (SEQ / CHUNKS)  // 128 rows (seq positions) per block

// One block handles one (bucket, seq-chunk). bucket = b*4 + src is
// block-uniform, so each thread keeps a single fp32 accumulator and the
// block does exactly one global atomicAdd into ws[bucket].
//
// Row base element offset = ((b*SEQ + s)*SRC + src)*DIM. Since DIM=257 ≡ 1
// (mod 4), base mod 4 == src for every row of this bucket → peel k0=(4-src)&3
// scalar elements, then the remaining bulk is 16B-aligned float4.
__global__ __launch_bounds__(256) void bucket_sq_sums(
    const float* __restrict__ pred,
    const float* __restrict__ gt,
    float* __restrict__ ws)
{
    const int bucket = blockIdx.x;          // 0..63
    const int b      = bucket >> 2;
    const int src    = bucket & 3;
    const int chunk  = blockIdx.y;          // 0..CHUNKS-1
    const int wave   = threadIdx.x >> 6;    // 0..3
    const int lane   = threadIdx.x & 63;

    const int k0    = (4 - src) & 3;        // prologue scalars to reach 16B align
    const int n4    = (DIM - k0) >> 2;      // 63 or 64 float4 per row
    const int nscal = DIM - (n4 << 2);      // k0 + tail scalars: 1 or 5

    float acc = 0.0f;

    for (int r = wave; r < ROWS_PER_BLOCK; r += 4) {
        const int s_seq = chunk * ROWS_PER_BLOCK + r;
        const long long base =
            ((long long)(b * SEQ + s_seq) * SRC + src) * (long long)DIM;

        if (lane < n4) {
            const float4* p4 = (const float4*)(pred + base + k0);
            const float4* g4 = (const float4*)(gt   + base + k0);
            float4 p = p4[lane];
            float4 g = g4[lane];
            float dx = p.x - g.x;
            float dy = p.y - g.y;
            float dz = p.z - g.z;
            float dw = p.w - g.w;
            acc += dx * dx + dy * dy + dz * dz + dw * dw;
        }
        if (lane < nscal) {
            // prologue scalars [0, k0), tail scalars [k0 + 4*n4, 257)
            const int off = (lane < k0) ? lane : (k0 + (n4 << 2) + (lane - k0));
            const float d = pred[base + off] - gt[base + off];
            acc += d * d;
        }
    }

    // wave64 shuffle reduction
    #pragma unroll
    for (int o = 32; o > 0; o >>= 1) acc += __shfl_down(acc, o, 64);

    __shared__ float s[4];
    if (lane == 0) s[wave] = acc;
    __syncthreads();
    if (threadIdx.x == 0) {
        atomicAdd(&ws[bucket], s[0] + s[1] + s[2] + s[3]);
    }
}

// Single wave: sqrt each bucket sum, reduce, write scalar output.
__global__ void finalize_kernel(const float* __restrict__ ws,
                                float* __restrict__ out)
{
    const int t = threadIdx.x;              // 0..63 == NBUCKET
    float v = sqrtf(ws[t]);
    #pragma unroll
    for (int o = 32; o > 0; o >>= 1) v += __shfl_down(v, o, 64);
    if (t == 0) out[0] = v;
}

extern "C" void kernel_launch(void* const* d_in, const int* in_sizes, int n_in,
                              void* d_out, int out_size, void* d_ws, size_t ws_size,
                              hipStream_t stream)
{
    const float* pred = (const float*)d_in[0];
    const float* gt   = (const float*)d_in[1];
    float* ws  = (float*)d_ws;
    float* out = (float*)d_out;

    // d_ws is re-poisoned (0xAA) before every timed launch — zero the 64
    // bucket accumulators on-stream (memset nodes are graph-capturable).
    hipMemsetAsync(ws, 0, NBUCKET * sizeof(float), stream);

    bucket_sq_sums<<<dim3(NBUCKET, CHUNKS), 256, 0, stream>>>(pred, gt, ws);
    finalize_kernel<<<1, 64, 0, stream>>>(ws, out);
}